// Round 4
// baseline (101.937 us; speedup 1.0000x reference)
//
#include <hip/hip_runtime.h>
#include <cstdint>

// CharEmb: per word (B*S=16384): gather 32 char embeddings (E=64) -> x[64][32]
// (raw view of [32 chars][64] buffer), conv1d(F=128,K=3,valid,T=30), bias,
// max over t. Output float32 [16384][128].
//
// MFMA 32x32x16 bf16, M=t, N=f (layouts VERIFIED round 1, absmax 0.031):
//   D[t][f] = sum_kk sum_e xT[t+kk][e] * W[f][e][kk]
// xT[c][e] in LDS bf16, row stride 72; conv shift t+kk = LDS addr offset.
// A frag: A[m=lane&31][k=h*8+j]; B frag: B[k][n=lane&31];
// C/D: col=lane&31, t=(reg&3)+8*(reg>>2)+4*h; t=30,31 (regs 14,15 on h=1) masked.
//
// Round 4: TEAM-OF-2 waves. MFMA throughput is per-CU (~8cyc/mfma) -> floor
// 10.3us; round 3's 1 wave/SIMD exposed all latency (MfmaUtil 21%). Now:
//  - block = 4 waves = 2 teams; team owns 2 words/group; each wave computes
//    2 n-tiles (64 f) for BOTH team words -> 4 indep MFMA chains/wave,
//    A read once per wave = 24 A-reads/word (r2: 48, r3: 12).
//  - ~210 regs -> 2 waves/SIMD (launch_bounds(256,2)), 39.2KB LDS -> 2 blk/CU.
//  - weights loaded direct from conv_w per wave (one-time, L2): no prep
//    kernel, no workspace use.

typedef __bf16 bf16x8 __attribute__((ext_vector_type(8)));
typedef float  f32x16 __attribute__((ext_vector_type(16)));

#define NW   16          // words per block; 1024 blocks
#define GW   4           // words staged per barrier group
#define NGRP 4
#define ROWS 34          // rows 0..31 written; 32,33 junk -> feed masked t=30,31 only
#define RST  72          // row stride in bf16 (36 dwords)
#define BUFE (ROWS * RST)

__global__ __launch_bounds__(256, 2)
void charcnn_mfma(const int* __restrict__ cid, const float* __restrict__ emb,
                  const float* __restrict__ wgt, const float* __restrict__ bias,
                  float* __restrict__ out) {
  // 8 word-buffers (two groups of 4): 8 * 34*72 bf16 = 39168 B
  __shared__ __align__(16) __bf16 xT[8][BUFE];

  const int tid  = threadIdx.x;
  const int lane = tid & 63;
  const int wv   = tid >> 6;
  const int m    = lane & 31;      // t-row / f-within-tile
  const int h    = lane >> 5;      // 0..1
  const int team = wv >> 1;        // 0..1 -> which word pair of the group
  const int half = wv & 1;         // 0..1 -> n-tiles {2h, 2h+1}

  // B fragments direct from conv_w [F=128][E=64][K=3]:
  // bfrag[u][kk*4+ks][j] = w[f=(2*half+u)*32+m][e=ks*16+h*8+j][kk]
  bf16x8 bfrag[2][12];
#pragma unroll
  for (int u = 0; u < 2; ++u) {
    const float* wf = wgt + ((2 * half + u) * 32 + m) * 192 + h * 24;
#pragma unroll
    for (int kk = 0; kk < 3; ++kk)
#pragma unroll
      for (int ks = 0; ks < 4; ++ks) {
        bf16x8 fr;
#pragma unroll
        for (int j = 0; j < 8; ++j)
          fr[j] = (__bf16)wf[(ks * 16 + j) * 3 + kk];
        bfrag[u][kk * 4 + ks] = fr;
      }
  }

  float vb[2];
  vb[0] = bias[(2 * half) * 32 + m];
  vb[1] = bias[(2 * half + 1) * 32 + m];

  // staging map: thread -> (char a, float4 index p)
  const int a  = tid >> 3;         // 0..31
  const int p  = tid & 7;          // 0..7
  const int bw = blockIdx.x * NW;

  // stage 4 words of group g into buffers (g&1)*4 + 0..3:
  // xT[c][2a]=emb[ch[a]][c], xT[c][2a+1]=emb[ch[a]][32+c]
  auto stage_group = [&](int g) {
    const int w0 = g * GW;
    int ch[GW];
#pragma unroll
    for (int i = 0; i < GW; ++i)
      ch[i] = cid[(bw + w0 + i) * 32 + a];
#pragma unroll
    for (int i = 0; i < GW; ++i) {
      const float4* er = (const float4*)(emb + ch[i] * 64);
      float4 lo = er[p];          // dims c = 4p..4p+3
      float4 hi = er[p + 8];      // dims 32+c
      uint32_t* dst = (uint32_t*)(&xT[(g & 1) * 4 + i][0]);
      float lv[4] = {lo.x, lo.y, lo.z, lo.w};
      float hv[4] = {hi.x, hi.y, hi.z, hi.w};
#pragma unroll
      for (int i2 = 0; i2 < 4; ++i2) {
        uint32_t u = ((uint32_t)__builtin_bit_cast(uint16_t, (__bf16)hv[i2]) << 16)
                   |  (uint32_t)__builtin_bit_cast(uint16_t, (__bf16)lv[i2]);
        dst[(4 * p + i2) * 36 + a] = u;    // dword idx: row*36 + colpair
      }
    }
  };

  auto compute_group = [&](int g) {
    const __bf16* xA = &xT[(g & 1) * 4 + team * 2][0];
    const __bf16* xB = &xT[(g & 1) * 4 + team * 2 + 1][0];
    f32x16 acc[2][2];                 // [word][ntile]
#pragma unroll
    for (int wi = 0; wi < 2; ++wi)
#pragma unroll
      for (int u = 0; u < 2; ++u)
#pragma unroll
        for (int r = 0; r < 16; ++r) acc[wi][u][r] = 0.0f;

#pragma unroll
    for (int kk = 0; kk < 3; ++kk) {
#pragma unroll
      for (int ks = 0; ks < 4; ++ks) {
        const int off = (m + kk) * RST + ks * 16 + h * 8;
        bf16x8 afA = *(const bf16x8*)(xA + off);
        bf16x8 afB = *(const bf16x8*)(xB + off);
        acc[0][0] = __builtin_amdgcn_mfma_f32_32x32x16_bf16(afA, bfrag[0][kk*4+ks], acc[0][0], 0, 0, 0);
        acc[0][1] = __builtin_amdgcn_mfma_f32_32x32x16_bf16(afA, bfrag[1][kk*4+ks], acc[0][1], 0, 0, 0);
        acc[1][0] = __builtin_amdgcn_mfma_f32_32x32x16_bf16(afB, bfrag[0][kk*4+ks], acc[1][0], 0, 0, 0);
        acc[1][1] = __builtin_amdgcn_mfma_f32_32x32x16_bf16(afB, bfrag[1][kk*4+ks], acc[1][1], 0, 0, 0);
      }
    }

    // max over t: t=(reg&3)+8*(reg>>2)+4h; regs 14,15 on h=1 are t=30,31.
    const int wg = bw + g * GW + team * 2;
#pragma unroll
    for (int wi = 0; wi < 2; ++wi) {
#pragma unroll
      for (int u = 0; u < 2; ++u) {
        float m0 = acc[wi][u][0];
#pragma unroll
        for (int r = 1; r <= 13; ++r) m0 = fmaxf(m0, acc[wi][u][r]);
        float m1 = fmaxf(acc[wi][u][14], acc[wi][u][15]);
        float mm = (lane < 32) ? fmaxf(m0, m1) : m0;
        float ot = __shfl_xor(mm, 32, 64);
        float res = fmaxf(mm, ot) + vb[u];
        if (lane < 32) out[(wg + wi) * 128 + (2 * half + u) * 32 + m] = res;
      }
    }
  };

  stage_group(0);
  __syncthreads();
#pragma unroll 1
  for (int g = 0; g < NGRP; ++g) {
    if (g + 1 < NGRP) stage_group(g + 1);   // global loads overlap MFMAs
    compute_group(g);
    __syncthreads();
  }
}

extern "C" void kernel_launch(void* const* d_in, const int* in_sizes, int n_in,
                              void* d_out, int out_size, void* d_ws, size_t ws_size,
                              hipStream_t stream) {
  const int*   cid = (const int*)d_in[0];    // [32*512*32] int32
  const float* emb = (const float*)d_in[1];  // [101*64]  f32
  const float* cw  = (const float*)d_in[2];  // [128*64*3] f32
  const float* cb  = (const float*)d_in[3];  // [128] f32
  float* outp = (float*)d_out;               // [16384*128] f32
  (void)d_ws; (void)ws_size;

  hipLaunchKernelGGL(charcnn_mfma, dim3(1024), dim3(256), 0, stream,
                     cid, emb, cw, cb, outp);
}

// Round 5
// 88.322 us; speedup vs baseline: 1.1541x; 1.1541x over previous
//
#include <hip/hip_runtime.h>
#include <cstdint>

// CharEmb: per word (B*S=16384): gather 32 char embeddings (E=64) -> x[64][32]
// (raw view of [32 chars][64] buffer), conv1d(F=128,K=3,valid,T=30), bias,
// max over t. Output float32 [16384][128].
//
// MFMA 32x32x16 bf16, M=t, N=f (layouts VERIFIED r1, absmax 0.031):
//   D[t][f] = sum_kk sum_e xT[t+kk][e] * W[f][e][kk]
// xT[c][e] in LDS bf16, row stride 72 (36 dwords); conv shift = LDS addr offset.
// A frag: A[m=lane&31][k=h*8+j]; B frag: B[k][n=lane&31] (prep-packed in ws);
// C/D: col=lane&31, t=(reg&3)+8*(reg>>2)+4*h; t=30,31 (regs 14,15 h=1) masked.
//
// Round 5 = round 2 structure (best measured: ~31us kernel) + two fixes:
//  - TLP lesson (r3/r4): regs = 64*ntiles+misc; n=1 -> ~125 regs -> 4 waves/SIMD.
//    n=2 (r4) gave 2 waves/SIMD and LOST despite half the LDS reads. Keep n=1.
//  - FIX 1: staging-write mapping char=tid&31 (was tid>>3): bank =
//    (16p+4i2+a)%32 now spans all 32 banks per half-wave -> 1.57M conflict
//    cycles -> ~0 (r4 counter evidence; r3 mapping measured conflict-free).
//  - FIX 2: preload all 16 cids to regs at start; in-loop staging chain is
//    then L1-resident emb load -> LDS write (emb table 25.8KB), not
//    HBM-cid -> emb -> write.

typedef __bf16 bf16x8 __attribute__((ext_vector_type(8)));
typedef float  f32x16 __attribute__((ext_vector_type(16)));

#define NW   16          // words per block; 1024 blocks
#define GW   4           // words staged per barrier group
#define NGRP 4
#define ROWS 34          // rows 0..31 written; 32,33 junk -> feed masked t=30,31
#define RST  72          // row stride in bf16 (36 dwords)
#define BUFE (ROWS * RST)

// Pack conv_w [F=128][E=64][K=3] fp32 -> B-fragment-ordered bf16 in ws:
// pw[((nt*12 + kk*4 + ks)*64 + lane)*8 + j]
//   = w[f=nt*32+(lane&31)][e=ks*16+(lane>>5)*8+j][kk]
__global__ __launch_bounds__(256)
void prep_pack_w(const float* __restrict__ w, __bf16* __restrict__ pw) {
  int i = blockIdx.x * 256 + threadIdx.x;   // 0..24575
  int j    = i & 7;
  int lane = (i >> 3) & 63;
  int ks   = (i >> 9) & 3;
  int t    = i >> 11;        // nt*3 + kk
  int kk   = t % 3;
  int nt   = t / 3;
  int f = nt * 32 + (lane & 31);
  int e = ks * 16 + (lane >> 5) * 8 + j;
  pw[i] = (__bf16)w[f * 192 + e * 3 + kk];
}

__global__ __launch_bounds__(256, 4)
void charcnn_mfma(const int* __restrict__ cid, const float* __restrict__ emb,
                  const float* __restrict__ bias, const __bf16* __restrict__ pw,
                  float* __restrict__ out) {
  // 8 word-buffers (two groups of 4): 8 * 34*72 bf16 = 39168 B -> 4 blocks/CU
  __shared__ __align__(16) __bf16 xT[8][BUFE];

  const int tid  = threadIdx.x;
  const int lane = tid & 63;
  const int wv   = tid >> 6;          // wave id == n-tile (f block of 32)
  const int m    = lane & 31;
  const int h    = lane >> 5;

  // persistent B fragments (weights), 12 frags = 48 VGPRs
  bf16x8 bfrag[12];
  const bf16x8* pwv = (const bf16x8*)pw;
#pragma unroll
  for (int q = 0; q < 12; ++q)        // q = kk*4 + ks
    bfrag[q] = pwv[(wv * 12 + q) * 64 + lane];

  const float vb = bias[wv * 32 + m];

  // staging map (FIX 1): char a = tid&31, float4-slot p = tid>>5 (0..7)
  const int a  = tid & 31;
  const int p  = tid >> 5;
  const int bw = blockIdx.x * NW;

  // FIX 2: preload this thread's char id for all 16 words (16 VGPRs).
  int ch[NW];
#pragma unroll
  for (int w = 0; w < NW; ++w) ch[w] = cid[(bw + w) * 32 + a];

  // stage 4 words of group g into buffers (g&1)*4 + 0..3:
  // dword[c*36 + a] = pack(emb[ch[a]][c], emb[ch[a]][32+c]), c = 4p..4p+3
  auto stage_group = [&](int g) {
    const int w0 = g * GW;
#pragma unroll
    for (int i = 0; i < GW; ++i) {
      const float4* er = (const float4*)(emb + ch[w0 + i] * 64);
      float4 lo = er[p];          // dims c = 4p..4p+3
      float4 hi = er[p + 8];      // dims 32+c
      uint32_t* dst = (uint32_t*)(&xT[(g & 1) * 4 + i][0]);
      float lv[4] = {lo.x, lo.y, lo.z, lo.w};
      float hv[4] = {hi.x, hi.y, hi.z, hi.w};
#pragma unroll
      for (int i2 = 0; i2 < 4; ++i2) {
        uint32_t u = ((uint32_t)__builtin_bit_cast(uint16_t, (__bf16)hv[i2]) << 16)
                   |  (uint32_t)__builtin_bit_cast(uint16_t, (__bf16)lv[i2]);
        dst[(4 * p + i2) * 36 + a] = u;   // bank=(16p+4i2+a)%32: conflict-free
      }
    }
  };

  auto compute_word = [&](int buf, int w) {
    const __bf16* xb = &xT[buf][0];
    f32x16 acc;
#pragma unroll
    for (int r = 0; r < 16; ++r) acc[r] = 0.0f;

#pragma unroll
    for (int kk = 0; kk < 3; ++kk) {
#pragma unroll
      for (int ks = 0; ks < 4; ++ks) {
        // A[m][k] = xT[m+kk][ks*16 + h*8 + j]
        const bf16x8* ap = (const bf16x8*)(xb + (m + kk) * RST + ks * 16 + h * 8);
        acc = __builtin_amdgcn_mfma_f32_32x32x16_bf16(*ap, bfrag[kk * 4 + ks],
                                                      acc, 0, 0, 0);
      }
    }

    // max over t: t=(reg&3)+8*(reg>>2)+4h; regs 14,15 on h=1 are t=30,31.
    float m0 = acc[0];
#pragma unroll
    for (int r = 1; r <= 13; ++r) m0 = fmaxf(m0, acc[r]);
    float m1 = fmaxf(acc[14], acc[15]);
    float mm = (lane < 32) ? fmaxf(m0, m1) : m0;
    float ot = __shfl_xor(mm, 32, 64);
    float res = fmaxf(mm, ot) + vb;
    if (lane < 32) out[(bw + w) * 128 + wv * 32 + m] = res;
  };

  stage_group(0);
  __syncthreads();
#pragma unroll 1
  for (int g = 0; g < NGRP; ++g) {
    if (g + 1 < NGRP) stage_group(g + 1);   // emb loads overlap MFMAs below
#pragma unroll
    for (int i = 0; i < GW; ++i)
      compute_word((g & 1) * 4 + i, g * GW + i);
    __syncthreads();
  }
}

extern "C" void kernel_launch(void* const* d_in, const int* in_sizes, int n_in,
                              void* d_out, int out_size, void* d_ws, size_t ws_size,
                              hipStream_t stream) {
  const int*   cid = (const int*)d_in[0];    // [32*512*32] int32
  const float* emb = (const float*)d_in[1];  // [101*64]  f32
  const float* cw  = (const float*)d_in[2];  // [128*64*3] f32
  const float* cb  = (const float*)d_in[3];  // [128] f32
  float* outp = (float*)d_out;               // [16384*128] f32
  __bf16* pw = (__bf16*)d_ws;                // 24576 bf16 = 48 KB

  hipLaunchKernelGGL(prep_pack_w, dim3(96), dim3(256), 0, stream, cw, pw);
  hipLaunchKernelGGL(charcnn_mfma, dim3(1024), dim3(256), 0, stream,
                     cid, emb, cb, (const __bf16*)pw, outp);
}